// Round 5
// baseline (589.648 us; speedup 1.0000x reference)
//
#include <hip/hip_runtime.h>
#include <hip/hip_bf16.h>

// Sizes (compile-time)
#define B_ 16
#define N_ 1024
#define CIN 24
#define EMB_ 64
#define HID_ 32
#define OUT_ 12
#define BH_ 32            // B*HEADS
#define RSQRT12 0.28867513459481287f
#define L2E 1.4426950408889634f

typedef float f2 __attribute__((ext_vector_type(2)));

// ---------------- workspace layout (floats) ----------------
#define OFF_Q      0              // 393216 (reused as t1o after edge_stats)
#define OFF_K      393216         // 393216 (reused as t1i after edge_stats)
#define OFF_M      786432         // 32768
#define OFF_ZI     819200         // 32768
#define OFF_DEG    851968         // 2048
#define OFF_INT    854016         // int area (rp/cp/eids)
#define OFF_TEMP   2689024        // 1048576
#define OFF_WFT    3737600        // 12288
#define OFF_BF     3749888        // 128
#define OFF_XP     3750016        // 1572864

// ---------------- fused: qk projection (blocks 1..384) + graph prep/wfold (block 0) ----------------
__global__ __launch_bounds__(1024) void qk_prep_kernel(
    const float* __restrict__ x, const float* __restrict__ Wq, const float* __restrict__ bq,
    const float* __restrict__ Wk, const float* __restrict__ bk,
    float* __restrict__ q, float* __restrict__ k,
    const int* __restrict__ ei, int E,
    float* __restrict__ deg, int* __restrict__ rp, int* __restrict__ cp,
    int* __restrict__ eids,
    const float* __restrict__ We, const float* __restrict__ be,
    const float* __restrict__ Wih, const float* __restrict__ bih,
    float* __restrict__ WfT, float* __restrict__ bf) {
  __shared__ int cntL[1024];
  __shared__ int sL[1024];
  __shared__ int offL[1024];
  int tid = threadIdx.x;
  if (blockIdx.x == 0) {
    deg[tid] = 0.f; deg[N_ + tid] = 0.f;
    cntL[tid] = 0;
    { int lo = 0, hi2 = E;
      while (lo < hi2) { int mid = (lo + hi2) >> 1; if (ei[mid] < tid) lo = mid + 1; else hi2 = mid; }
      rp[tid] = lo; }
    if (tid == 0) rp[N_] = E;
    __syncthreads();
    for (int e = tid; e < E; e += 1024) atomicAdd(&cntL[ei[E + e]], 1);
    __syncthreads();
    int my = cntL[tid];
    sL[tid] = my;
    __syncthreads();
    for (int d = 1; d < 1024; d <<= 1) {
      int v = (tid >= d) ? sL[tid - d] : 0;
      __syncthreads();
      sL[tid] += v;
      __syncthreads();
    }
    int excl = sL[tid] - my;
    cp[tid] = excl;
    offL[tid] = excl;
    if (tid == 1023) cp[1024] = sL[tid];
    __syncthreads();
    for (int e = tid; e < E; e += 1024) {
      int p = atomicAdd(&offL[ei[E + e]], 1);
      eids[p] = e;
    }
    for (int i = tid; i < 128 * 96; i += 1024) {
      int o = i % 96, c = i / 96;
      float acc = 0.f;
#pragma unroll
      for (int e = 0; e < 12; e++) acc += Wih[o * 12 + e] * We[e * 128 + c];
      WfT[c * 96 + o] = acc * ((o < 64) ? L2E : 2.f * L2E);
    }
    if (tid < 96) {
      float acc = bih[tid];
#pragma unroll
      for (int e = 0; e < 12; e++) acc += Wih[tid * 12 + e] * be[e];
      bf[tid] = acc * ((tid < 64) ? L2E : 2.f * L2E);
    }
  } else {
    int t = (blockIdx.x - 1) * 1024 + tid;
    int bi = t / CIN, c = t % CIN;
    int b = bi >> 10, i = bi & (N_ - 1);
    const float* xr = x + bi * CIN;
    float aq = bq[c], ak = bk[c];
#pragma unroll
    for (int d = 0; d < CIN; d++) {
      float xv = xr[d];
      aq += xv * Wq[c * CIN + d];
      ak += xv * Wk[c * CIN + d];
    }
    int h = c / 12, cc = c - h * 12;
    int qi = ((b * 2 + h) * N_ + i) * 12 + cc;
    q[qi] = aq;
    k[qi] = ak;
  }
}

// ---------------- fused: row softmax stats (blocks 0..511) + TCN (blocks 512..767) ----------------
#define TW 72  // 64 + halo 6 + pad 2
__global__ __launch_bounds__(512) void lse_tcn_kernel(
    const float* __restrict__ q, const float* __restrict__ k,
    float* __restrict__ mrow, float* __restrict__ zinv,
    const float* __restrict__ x,
    const float* __restrict__ c1w0, const float* __restrict__ c1b0,
    const float* __restrict__ c2w0, const float* __restrict__ c2b0,
    const float* __restrict__ dw0, const float* __restrict__ db0,
    const float* __restrict__ c1w1, const float* __restrict__ c1b1,
    const float* __restrict__ c2w1, const float* __restrict__ c2b1,
    float* __restrict__ temporal) {
  __shared__ __align__(16) char smem[53248];
  int tid = threadIdx.x;
  if (blockIdx.x < 512) {
    float* ks = (float*)smem;                       // 12288 floats
    float (*pm)[64] = (float(*)[64])(smem + 49152);
    float (*pz)[64] = (float(*)[64])(smem + 51200);
    int bh = blockIdx.x >> 4;
    int rg = blockIdx.x & 15;
    const float4* k4 = (const float4*)(k + bh * N_ * 12);
    float4* ks4 = (float4*)ks;
    for (int i = tid; i < N_ * 3; i += 512) ks4[i] = k4[i];
    int wave = tid >> 6, lane = tid & 63;
    int row = rg * 64 + lane;
    float qr[12];
    const float* qp = q + (bh * N_ + row) * 12;
#pragma unroll
    for (int c = 0; c < 12; c++) qr[c] = qp[c];
    __syncthreads();
    float mloc = -1e30f, zloc = 0.f;
    for (int j = wave * 128; j < wave * 128 + 128; j++) {
      const float* kj = ks + j * 12;
      float s = 0.f;
#pragma unroll
      for (int c = 0; c < 12; c++) s += qr[c] * kj[c];
      s *= RSQRT12;
      float mn = fmaxf(mloc, s);
      zloc = zloc * __expf(mloc - mn) + __expf(s - mn);
      mloc = mn;
    }
    pm[wave][lane] = mloc;
    pz[wave][lane] = zloc;
    __syncthreads();
    if (tid < 64) {
      float M = pm[0][tid];
#pragma unroll
      for (int w2 = 1; w2 < 8; w2++) M = fmaxf(M, pm[w2][tid]);
      float Z = 0.f;
#pragma unroll
      for (int w2 = 0; w2 < 8; w2++) Z += pz[w2][tid] * __expf(pm[w2][tid] - M);
      mrow[bh * N_ + rg * 64 + tid] = M;
      zinv[bh * N_ + rg * 64 + tid] = 1.f / Z;
    }
  } else {
    // ---- TCN tile: thread = (g, co); co = tid&63 so in-reads broadcast, stores coalesce
    float* xs   = (float*)smem;        // 24*72
    float* bufA = xs + CIN * TW;       // 64*72
    float* bufB = bufA + 64 * TW;      // 64*72
    int tb = blockIdx.x - 512;
    int b = tb >> 4;
    int t0 = (tb & 15) << 6;
    int co = tid & 63, g = tid >> 6;   // g in 0..7
    for (int i = tid; i < CIN * TW; i += 512) {
      int ln = i / CIN, c = i % CIN;
      int n = t0 - 6 + ln;
      xs[c * TW + ln] = (n >= 0 && n < N_) ? x[(b * N_ + n) * CIN + c] : 0.f;
    }
    __syncthreads();
    // L1: d=1, llo=1, in xs (24ch), out bufB
    {
      int lbase = 1 + g * 9;
      float acc[9];
      float bias = c1b0[co];
#pragma unroll
      for (int kk = 0; kk < 9; kk++) acc[kk] = bias;
      const float* wrow = c1w0 + co * 48;
      for (int ci = 0; ci < 24; ci++) {
        float w0 = wrow[ci * 2], w1 = wrow[ci * 2 + 1];
        const float* in = xs + ci * TW + lbase;
        float prev = in[-1];
#pragma unroll
        for (int kk = 0; kk < 9; kk++) { float cur = in[kk]; acc[kk] += w0 * prev + w1 * cur; prev = cur; }
      }
#pragma unroll
      for (int kk = 0; kk < 9; kk++) {
        int ln = lbase + kk;
        if (ln < TW) { int n = t0 - 6 + ln; bufB[co * TW + ln] = (n >= 0) ? fmaxf(acc[kk], 0.f) : 0.f; }
      }
    }
    __syncthreads();
    // L2 + downsample: d=1, llo=2, in bufB(64)+xs(24), out bufA
    {
      int lbase = 2 + g * 9;
      float acc[9], ds[9];
      float bias = c2b0[co], dbias = db0[co];
#pragma unroll
      for (int kk = 0; kk < 9; kk++) { acc[kk] = bias; ds[kk] = dbias; }
      const float* wrow = c2w0 + co * 128;
      for (int ci = 0; ci < 64; ci++) {
        float w0 = wrow[ci * 2], w1 = wrow[ci * 2 + 1];
        const float* in = bufB + ci * TW + lbase;
        float prev = in[-1];
#pragma unroll
        for (int kk = 0; kk < 9; kk++) { float cur = in[kk]; acc[kk] += w0 * prev + w1 * cur; prev = cur; }
      }
      const float* wd = dw0 + co * 24;
      for (int ci = 0; ci < 24; ci++) {
        float wv = wd[ci];
        const float* in = xs + ci * TW + lbase;
#pragma unroll
        for (int kk = 0; kk < 9; kk++) ds[kk] += wv * in[kk];
      }
#pragma unroll
      for (int kk = 0; kk < 9; kk++) {
        int ln = lbase + kk;
        if (ln < TW) {
          int n = t0 - 6 + ln;
          float v = fmaxf(fmaxf(acc[kk], 0.f) + ds[kk], 0.f);
          bufA[co * TW + ln] = (n >= 0) ? v : 0.f;
        }
      }
    }
    __syncthreads();
    // L3: d=2, llo=4, in bufA, out bufB
    {
      int lbase = 4 + g * 9;
      float acc[9];
      float bias = c1b1[co];
#pragma unroll
      for (int kk = 0; kk < 9; kk++) acc[kk] = bias;
      const float* wrow = c1w1 + co * 128;
      for (int ci = 0; ci < 64; ci++) {
        float w0 = wrow[ci * 2], w1 = wrow[ci * 2 + 1];
        const float* in = bufA + ci * TW + lbase;
        float p2 = in[-2], p1 = in[-1];
#pragma unroll
        for (int kk = 0; kk < 9; kk++) { float cur = in[kk]; acc[kk] += w0 * p2 + w1 * cur; p2 = p1; p1 = cur; }
      }
#pragma unroll
      for (int kk = 0; kk < 9; kk++) {
        int ln = lbase + kk;
        if (ln < TW) { int n = t0 - 6 + ln; bufB[co * TW + ln] = (n >= 0) ? fmaxf(acc[kk], 0.f) : 0.f; }
      }
    }
    __syncthreads();
    // L4 + residual: d=2, ln in [6,70), 8 outputs/thread, write temporal
    {
      int lbase = 6 + g * 8;
      float acc[8];
      float bias = c2b1[co];
#pragma unroll
      for (int kk = 0; kk < 8; kk++) acc[kk] = bias;
      const float* wrow = c2w1 + co * 128;
      for (int ci = 0; ci < 64; ci++) {
        float w0 = wrow[ci * 2], w1 = wrow[ci * 2 + 1];
        const float* in = bufB + ci * TW + lbase;
        float p2 = in[-2], p1 = in[-1];
#pragma unroll
        for (int kk = 0; kk < 8; kk++) { float cur = in[kk]; acc[kk] += w0 * p2 + w1 * cur; p2 = p1; p1 = cur; }
      }
#pragma unroll
      for (int kk = 0; kk < 8; kk++) {
        int ln = lbase + kk;
        float v = fmaxf(fmaxf(acc[kk], 0.f) + bufA[co * TW + ln], 0.f);
        temporal[(b * N_ + t0 + ln - 6) * 64 + co] = v;
      }
    }
  }
}

// ---------------- edge stats: one (edge, bh) per thread, shuffle-reduce over bh ----------------
__global__ __launch_bounds__(256) void edge_stats_kernel(
    const float* __restrict__ q, const float* __restrict__ k,
    const float* __restrict__ mrow, const float* __restrict__ zinv,
    const int* __restrict__ ei, const float* __restrict__ ewt, int E,
    float* __restrict__ deg) {
  int t = blockIdx.x * 256 + threadIdx.x;
  int e = t >> 5, bh = t & 31;
  if (e >= E) return;
  int src = ei[e], dst = ei[E + e];
  const float4* qp = (const float4*)(q + (bh * N_ + src) * 12);
  const float4* kp = (const float4*)(k + (bh * N_ + dst) * 12);
  float s = 0.f;
#pragma unroll
  for (int c4 = 0; c4 < 3; c4++) {
    float4 qv = qp[c4], kv = kp[c4];
    s += qv.x * kv.x + qv.y * kv.y + qv.z * kv.z + qv.w * kv.w;
  }
  s *= RSQRT12;
  float a = __expf(s - mrow[bh * N_ + src]) * zinv[bh * N_ + src];
  a += __shfl_xor(a, 16);
  a += __shfl_xor(a, 8);
  a += __shfl_xor(a, 4);
  a += __shfl_xor(a, 2);
  a += __shfl_xor(a, 1);
  if (bh == 0) {
    float w = 25.f * ewt[e] * (a * (1.f / 32.f));
    atomicAdd(&deg[src], w);
    atomicAdd(&deg[N_ + dst], w);
  }
}

// ---------------- fused atomic-free gathers for t1i (blocks 0..1023) / t1o (1024..2047) ----------------
__global__ __launch_bounds__(384) void gather_io_kernel(
    const float* __restrict__ x, const int* __restrict__ ei, int E,
    const int* __restrict__ rp, const int* __restrict__ cp, const int* __restrict__ eids,
    const float* __restrict__ deg,
    float* __restrict__ t1i, float* __restrict__ t1o) {
  __shared__ int nb[96];
  __shared__ float wv[96];
  bool isOut = blockIdx.x >= N_;
  int node = isOut ? (blockIdx.x - N_) : blockIdx.x;
  int e0 = isOut ? cp[node] : rp[node];
  int e1 = isOut ? cp[node + 1] : rp[node + 1];
  int tid = threadIdx.x;
  int b = tid / 24, c = tid % 24;
  float acc = 0.f;
  for (int base = e0; base < e1; base += 96) {
    int m = min(96, e1 - base);
    if (tid < m) {
      if (isOut) {
        int e = eids[base + tid];
        int sn = ei[e];
        nb[tid] = sn;
        wv[tid] = __builtin_amdgcn_rcpf(deg[sn]);
      } else {
        int d = ei[E + base + tid];
        nb[tid] = d;
        wv[tid] = __builtin_amdgcn_rcpf(deg[N_ + d]);
      }
    }
    __syncthreads();
    for (int t = 0; t < m; t++) acc += x[(b * N_ + nb[t]) * CIN + c] * wv[t];
    __syncthreads();
  }
  float* dst = isOut ? t1o : t1i;
  dst[(b * N_ + node) * CIN + c] = acc;
}

// ---------------- fused spatial + xp (LDS-broadcast structure) ----------------
__global__ __launch_bounds__(384) void spatxp_kernel(
    const float* __restrict__ x, const float* __restrict__ t1o, const float* __restrict__ t1i,
    const float* __restrict__ Wd, const float* __restrict__ bd,
    const float* __restrict__ temporal,
    const float* __restrict__ WfT, const float* __restrict__ bf,
    float* __restrict__ xp) {
  __shared__ float tmp_s[64 * 64];   // temporal tile [nl][c]
  __shared__ float spat_s[64 * 64];
  int b = blockIdx.x >> 4;
  int n0 = (blockIdx.x & 15) << 6;
  int tid = threadIdx.x;
  // stage temporal tile
  {
    const float4* t4 = (const float4*)(temporal + (size_t)(b * N_ + n0) * 64);
    float4* d4 = (float4*)tmp_s;
    for (int i = tid; i < 1024; i += 384) d4[i] = t4[i];
  }
  // spatial for 64 nodes x 64 ch
  for (int idx = tid; idx < 4096; idx += 384) {
    int nl = idx >> 6, o = idx & 63;
    int bi = (b * N_ + n0 + nl);
    const float* xr = x + bi * CIN;
    const float* ar = t1o + bi * CIN;
    const float* br = t1i + bi * CIN;
    float acc = bd[o];
#pragma unroll
    for (int d = 0; d < CIN; d++) {
      acc += xr[d] * (Wd[d * 64 + o] + Wd[3072 + d * 64 + o]);
      acc += ar[d] * Wd[1536 + d * 64 + o];
      acc += br[d] * Wd[4608 + d * 64 + o];
    }
    spat_s[nl * 64 + o] = fmaxf(acc, 0.f);
  }
  __syncthreads();
  // xp: thread (g,o); 16 nodes per thread; LDS reads broadcast across the 96 o-lanes
  {
    int g = tid / 96, o = tid - g * 96;
    float acc[16];
#pragma unroll
    for (int kk = 0; kk < 16; kk++) acc[kk] = bf[o];
    const float* tr = tmp_s + g * 16 * 64;
    const float* sr = spat_s + g * 16 * 64;
    for (int c = 0; c < 64; c++) {
      float w1 = WfT[c * 96 + o];
      float w2 = WfT[(64 + c) * 96 + o];
#pragma unroll
      for (int kk = 0; kk < 16; kk++) {
        acc[kk] = fmaf(tr[kk * 64 + c], w1, fmaf(sr[kk * 64 + c], w2, acc[kk]));
      }
    }
#pragma unroll
    for (int kk = 0; kk < 16; kk++)
      xp[(size_t)(b * N_ + n0 + g * 16 + kk) * 96 + o] = acc[kk];
  }
}

// ---------------- GRU scan: 2 batches per wave, lane-local gates, fused decoder ----------------
#define CHUNK2 32
__global__ __launch_bounds__(256) void gru_kernel(
    const float* __restrict__ xp, const float* __restrict__ Whh,
    const float* __restrict__ bhh, const float* __restrict__ Wdec,
    const float* __restrict__ bdec, float* __restrict__ out) {
  __shared__ float xbuf[2][2][CHUNK2 * 96];   // [batch][buf] 48 KB
  __shared__ float hbuf[2][2][CHUNK2 * 36];   // [batch][buf] 18 KB (stride 36, 16B-aligned rows)
  __shared__ float wdec_s[12 * 36];
  __shared__ float bdec_s[12];
  int b2 = blockIdx.x;               // 0..7
  int bx = 2 * b2;
  int tid = threadIdx.x;
  int wave = tid >> 6;
  const float* xpX = xp + (size_t)bx * N_ * 96;
  const float* xpY = xp + (size_t)(bx + 1) * N_ * 96;
  // stage chunk 0 (all threads) + decoder weights
  {
    const float4* sx = (const float4*)xpX;
    const float4* sy = (const float4*)xpY;
    float4* dx = (float4*)xbuf[0][0];
    float4* dy = (float4*)xbuf[1][0];
    for (int i = tid; i < CHUNK2 * 24; i += 256) { dx[i] = sx[i]; dy[i] = sy[i]; }
    if (tid < 12) bdec_s[tid] = bdec[tid];
    for (int i = tid; i < 384; i += 256) wdec_s[(i >> 5) * 36 + (i & 31)] = Wdec[i];
  }
  // wave0 per-lane weights: lane = H*32 + jl; 3 gate rows per lane (r=jl, z=32+jl, n=64+jl)
  f2 wr2[16], wz2[16], wn2[16];
  float bR = 0.f, bZ = 0.f, bN = 0.f, h = 0.f;
  int jl = tid & 31;
  int H = (tid >> 5) & 1;
  int bpbase = (tid & 32) << 2;      // ds_bpermute byte base: 0 or 128
  if (wave == 0) {
#pragma unroll
    for (int i = 0; i < 16; i++) {
      wr2[i] = f2{L2E * Whh[jl * 32 + 2 * i],        L2E * Whh[jl * 32 + 2 * i + 1]};
      wz2[i] = f2{L2E * Whh[(32 + jl) * 32 + 2 * i], L2E * Whh[(32 + jl) * 32 + 2 * i + 1]};
      wn2[i] = f2{2.f * L2E * Whh[(64 + jl) * 32 + 2 * i], 2.f * L2E * Whh[(64 + jl) * 32 + 2 * i + 1]};
    }
    bR = L2E * bhh[jl];
    bZ = L2E * bhh[32 + jl];
    bN = 2.f * L2E * bhh[64 + jl];
  }
  __syncthreads();
  for (int c = 0; c < 32; c++) {
    if (wave == 0) {
      const float* bufl = xbuf[H][c & 1];
      float* hb = hbuf[H][c & 1];
      float xr = bufl[jl], xz = bufl[32 + jl], xn = bufl[64 + jl];
      for (int ln = 0; ln < CHUNK2; ln++) {
        float nxr = 0.f, nxz = 0.f, nxn = 0.f;
        if (ln + 1 < CHUNK2) {
          const float* nb = bufl + (ln + 1) * 96;
          nxr = nb[jl]; nxz = nb[32 + jl]; nxn = nb[64 + jl];
        }
        f2 aR = f2{xr + bR, 0.f};
        f2 aZ = f2{xz + bZ, 0.f};
        f2 aN = f2{bN, 0.f};
        int hq = __float_as_int(h);
#pragma unroll
        for (int i = 0; i < 16; i++) {
          f2 hv;
          hv.x = __int_as_float(__builtin_amdgcn_ds_bpermute(bpbase + 8 * i, hq));
          hv.y = __int_as_float(__builtin_amdgcn_ds_bpermute(bpbase + 8 * i + 4, hq));
          aR = __builtin_elementwise_fma(wr2[i], hv, aR);
          aZ = __builtin_elementwise_fma(wz2[i], hv, aZ);
          aN = __builtin_elementwise_fma(wn2[i], hv, aN);
        }
        float gR = aR.x + aR.y;
        float gZ = aZ.x + aZ.y;
        float gN = aN.x + aN.y;
        float r = __builtin_amdgcn_rcpf(1.f + exp2f(-gR));
        float z = __builtin_amdgcn_rcpf(1.f + exp2f(-gZ));
        float t = exp2f(fmaf(r, gN, xn));
        float nn = fmaf(-2.f, __builtin_amdgcn_rcpf(t + 1.f), 1.f);  // tanh
        h = fmaf(z, h - nn, nn);
        hb[ln * 36 + jl] = h;
        xr = nxr; xz = nxz; xn = nxn;
      }
    } else {
      int t64 = tid - 64;
      if (c + 1 < 32) {
        const float4* sx = (const float4*)(xpX + (size_t)(c + 1) * CHUNK2 * 96);
        const float4* sy = (const float4*)(xpY + (size_t)(c + 1) * CHUNK2 * 96);
        float4* dx = (float4*)xbuf[0][(c + 1) & 1];
        float4* dy = (float4*)xbuf[1][(c + 1) & 1];
        for (int i = t64; i < CHUNK2 * 24; i += 192) { dx[i] = sx[i]; dy[i] = sy[i]; }
      }
      if (c > 0) {
        int half = t64 / 96, o96 = t64 - half * 96;
        const float* hb = hbuf[half][(c - 1) & 1];
        int n0b = (c - 1) * CHUNK2;
        int bb = bx + half;
#pragma unroll
        for (int qq = 0; qq < 4; qq++) {
          int idx = qq * 96 + o96;              // 0..383
          int nl = idx / 12, o = idx - nl * 12;
          const float4* h4 = (const float4*)(hb + nl * 36);
          const float4* w4 = (const float4*)(wdec_s + o * 36);
          float acc = bdec_s[o];
#pragma unroll
          for (int i = 0; i < 8; i++) {
            float4 hv = h4[i], wv = w4[i];
            acc += fmaxf(hv.x, 0.f) * wv.x + fmaxf(hv.y, 0.f) * wv.y +
                   fmaxf(hv.z, 0.f) * wv.z + fmaxf(hv.w, 0.f) * wv.w;
          }
          out[(size_t)(bb * N_ + n0b + nl) * 12 + o] = acc;
        }
      }
    }
    __syncthreads();
  }
  // decode last chunk (all 256 threads, 3 outputs each)
  {
    int n0b = 31 * CHUNK2;
#pragma unroll
    for (int qq = 0; qq < 3; qq++) {
      int idx = qq * 256 + tid;                 // < 768
      int half = idx / 384, r384 = idx - half * 384;
      int nl = r384 / 12, o = r384 - nl * 12;
      const float* hb = hbuf[half][1];
      const float4* h4 = (const float4*)(hb + nl * 36);
      const float4* w4 = (const float4*)(wdec_s + o * 36);
      float acc = bdec_s[o];
#pragma unroll
      for (int i = 0; i < 8; i++) {
        float4 hv = h4[i], wv = w4[i];
        acc += fmaxf(hv.x, 0.f) * wv.x + fmaxf(hv.y, 0.f) * wv.y +
               fmaxf(hv.z, 0.f) * wv.z + fmaxf(hv.w, 0.f) * wv.w;
      }
      out[(size_t)((bx + half) * N_ + n0b + nl) * 12 + o] = acc;
    }
  }
}

extern "C" void kernel_launch(void* const* d_in, const int* in_sizes, int n_in,
                              void* d_out, int out_size, void* d_ws, size_t ws_size,
                              hipStream_t stream) {
  const float* x    = (const float*)d_in[0];
  const int*   ei   = (const int*)d_in[2];
  const float* ewt  = (const float*)d_in[3];
  const float* Wq   = (const float*)d_in[4];
  const float* bq   = (const float*)d_in[5];
  const float* Wk   = (const float*)d_in[6];
  const float* bk   = (const float*)d_in[7];
  const float* Wd   = (const float*)d_in[8];
  const float* bd   = (const float*)d_in[9];
  const float* c1w0 = (const float*)d_in[10];
  const float* c1b0 = (const float*)d_in[11];
  const float* c2w0 = (const float*)d_in[12];
  const float* c2b0 = (const float*)d_in[13];
  const float* dw0  = (const float*)d_in[14];
  const float* db0  = (const float*)d_in[15];
  const float* c1w1 = (const float*)d_in[16];
  const float* c1b1 = (const float*)d_in[17];
  const float* c2w1 = (const float*)d_in[18];
  const float* c2b1 = (const float*)d_in[19];
  const float* We   = (const float*)d_in[20];
  const float* be   = (const float*)d_in[21];
  const float* Wih  = (const float*)d_in[22];
  const float* Whh  = (const float*)d_in[23];
  const float* bih  = (const float*)d_in[24];
  const float* bhh  = (const float*)d_in[25];
  const float* Wdec = (const float*)d_in[26];
  const float* bdec = (const float*)d_in[27];
  float* out = (float*)d_out;
  float* w = (float*)d_ws;
  const int E = in_sizes[2] / 2;

  float* q    = w + OFF_Q;
  float* k    = w + OFF_K;
  float* mrow = w + OFF_M;
  float* zinv = w + OFF_ZI;
  float* deg  = w + OFF_DEG;
  float* t1o  = w + OFF_Q;   // reuse after edge_stats
  float* t1i  = w + OFF_K;   // reuse after edge_stats
  float* temp = w + OFF_TEMP;
  float* WfT  = w + OFF_WFT;
  float* bf   = w + OFF_BF;
  float* xp   = w + OFF_XP;
  int* ib   = (int*)(w + OFF_INT);
  int* rp   = ib;            // 1025
  int* cp   = ib + 1028;     // 1025
  int* eids = ib + 2056;     // E

  qk_prep_kernel<<<385, 1024, 0, stream>>>(x, Wq, bq, Wk, bk, q, k,
                                           ei, E, deg, rp, cp, eids,
                                           We, be, Wih, bih, WfT, bf);
  lse_tcn_kernel<<<768, 512, 0, stream>>>(q, k, mrow, zinv, x,
                                          c1w0, c1b0, c2w0, c2b0, dw0, db0,
                                          c1w1, c1b1, c2w1, c2b1, temp);
  edge_stats_kernel<<<(E * 32 + 255) / 256, 256, 0, stream>>>(q, k, mrow, zinv, ei, ewt, E, deg);
  gather_io_kernel<<<2 * N_, 384, 0, stream>>>(x, ei, E, rp, cp, eids, deg, t1i, t1o);
  spatxp_kernel<<<B_ * 16, 384, 0, stream>>>(x, t1o, t1i, Wd, bd, temp, WfT, bf, xp);
  gru_kernel<<<8, 256, 0, stream>>>(xp, Whh, bhh, Wdec, bdec, out);
}